// Round 7
// baseline (714.117 us; speedup 1.0000x reference)
//
#include <hip/hip_runtime.h>
#include <hip/hip_bf16.h>

// Problem constants
#define BB 32
#define TT 1500
#define TP 1536      // T padded to 12*128 for GEMM tiles
#define EE 512
#define HH 4
#define AA 512
#define NN 2048      // H*A
#define CC 10
#define KCONV 201
#define KAUG 576     // 512 enc + 40 conv + 24 zero pad (18 k-steps of 32)

typedef __attribute__((ext_vector_type(8))) __bf16 bf16x8;
typedef __attribute__((ext_vector_type(4))) float f32x4;

// ---------- helpers ----------
__device__ __forceinline__ unsigned short f2bf(float x) {
    unsigned int u = __float_as_uint(x);
    u = (u + 0x7fffu + ((u >> 16) & 1u)) >> 16;   // RNE, inputs always finite
    return (unsigned short)u;
}
__device__ __forceinline__ float bf2f(unsigned short u) {
    return __uint_as_float(((unsigned int)u) << 16);
}
__device__ __forceinline__ void glds16(const void* g, void* l) {
    __builtin_amdgcn_global_load_lds(
        (const __attribute__((address_space(1))) unsigned int*)g,
        (__attribute__((address_space(3))) unsigned int*)l, 16, 0, 0);
}
// tanh(x) = 1 - 2/(e^{2x}+1); saturates correctly at +-inf; abs err ~1e-6.
__device__ __forceinline__ float tanh_fast(float x) {
    float e = __expf(x * 2.0f);
    return fmaf(-2.0f, __builtin_amdgcn_rcpf(e + 1.0f), 1.0f);
}
// packed f32x2 -> bf16x2 (RNE)
__device__ __forceinline__ unsigned int pkbf(float x, float y) {
    float2 f{x, y};
    __hip_bfloat162 h2 = __float22bfloat162_rn(f);
    return *reinterpret_cast<unsigned int*>(&h2);
}
// split pair into packed hi bf16x2 and packed lo (residual) bf16x2
__device__ __forceinline__ void split2(float x, float y, unsigned int& h, unsigned int& l) {
    unsigned short hx = f2bf(x), hy = f2bf(y);
    h = ((unsigned int)hy << 16) | hx;
    l = pkbf(x - bf2f(hx), y - bf2f(hy));
}

// Fused prep kernel: block-range dispatch of 4 phases.
//   [0,1024)       zero  energy + ctx_h (replaces hipMemsetAsync launch)
//   [1024,2048)    dec   dec_a[b][n]  (4-way K-split + LDS reduce)
//   [2048,9728)    conv  grouped conv -> Chi/Clo[b][t][0..40)
//   [9728,10016)   wt    W planes (LDS-transposed, coalesced both sides)
#define PREP_ZERO0  0
#define PREP_DEC0   1024
#define PREP_CONV0  2048
#define PREP_WT0    9728
#define PREP_TOTAL  10016

__global__ __launch_bounds__(256) void k_prep(
    const float* __restrict__ dec_out, const float* __restrict__ aw_step,
    const float* __restrict__ w_enc, const float* __restrict__ b_enc,
    const float* __restrict__ w_dec, const float* __restrict__ w_conv,
    const float* __restrict__ conv_k,
    unsigned short* __restrict__ Whi, unsigned short* __restrict__ Wlo,
    unsigned short* __restrict__ Chi, unsigned short* __restrict__ Clo,
    float* __restrict__ dec_a, float* __restrict__ zbase) {
    __shared__ float sh[64 * 65];   // wt transpose tile; aliased by dec/conv scratch
    const int bid = blockIdx.x;
    const int tid = threadIdx.x;

    if (bid < PREP_DEC0) {
        // ---- zero: energy (196608 f32) + ctx_h (65536 f32), contiguous ----
        zbase[bid * 256 + tid] = 0.f;
    } else if (bid < PREP_CONV0) {
        // ---- dec: dec_a[b][n] = b_enc[n] + sum_d dec[b][d]*w_dec[h][d][a] ----
        const int rb = bid - PREP_DEC0;
        const int b  = rb >> 5;
        const int n0 = (rb & 31) * 64;
        const int n  = n0 + (tid & 63);
        const int dg = tid >> 6;                   // 0..3, 128 d each
        const int h  = n >> 9, a = n & 511;
        const float* dp = dec_out + (size_t)b * 512 + dg * 128;
        const float* wp = w_dec + ((size_t)h * 512 + dg * 128) * 512 + a;
        float acc = 0.f;
#pragma unroll 8
        for (int d = 0; d < 128; ++d) acc += dp[d] * wp[(size_t)d * 512];
        sh[tid] = acc;
        __syncthreads();
        if (tid < 64) {
            float tot = sh[tid] + sh[tid + 64] + sh[tid + 128] + sh[tid + 192];
            dec_a[(size_t)b * NN + n0 + tid] = b_enc[n0 + tid] + tot;
        }
    } else if (bid < PREP_WT0) {
        // ---- conv: grouped 1D conv over aw_step -> Chi/Clo[b][t][hc] ----
        int r = bid - PREP_CONV0;                  // 7680 = 6*40*32
        const int tch = r % 6;
        const int hc  = (r / 6) % 40;
        const int b   = r / 240;
        const int h   = hc / 10;
        const int t0  = tch * 256;
        float* sAw = sh;
        for (int i = tid; i < 456; i += 256) {
            int ts = t0 - 100 + i;
            sAw[i] = (ts >= 0 && ts < TT) ? aw_step[((size_t)b * TT + ts) * HH + h] : 0.f;
        }
        __syncthreads();
        int t = t0 + tid;
        if (t < TT) {
            const float* ck = conv_k + (size_t)hc * KCONV;   // uniform index -> s_load
            float acc = 0.f;
#pragma unroll 4
            for (int k = 0; k < KCONV; ++k) acc += sAw[tid + k] * ck[k];
            size_t o = ((size_t)b * TP + t) * 64 + hc;
            unsigned short hi = f2bf(acc);
            Chi[o] = hi; Clo[o] = f2bf(acc - bf2f(hi));
        }
    } else {
        // ---- wt: W planes [N=2048][KAUG], hi/lo; coalesced via LDS transpose ----
        int r = bid - PREP_WT0;                    // 0..287 = 4h * 8a * 9k
        const int h  = r / 72;
        const int rr = r % 72;
        const int at = rr / 9;
        const int kt = rr % 9;
        const int a0 = at * 64;
        if (kt < 8) {
            const int k0 = kt * 64;
#pragma unroll
            for (int it = 0; it < 16; ++it) {
                int kk = it * 4 + (tid >> 6);
                int aa = tid & 63;
                sh[kk * 65 + aa] = w_enc[((size_t)h * 512 + k0 + kk) * 512 + a0 + aa];
            }
            __syncthreads();
#pragma unroll
            for (int it = 0; it < 16; ++it) {
                int nl = it * 4 + (tid >> 6);
                int kk = tid & 63;
                float val = sh[kk * 65 + nl];
                size_t o = ((size_t)h * 512 + a0 + nl) * KAUG + k0 + kk;
                unsigned short hi = f2bf(val);
                Whi[o] = hi; Wlo[o] = f2bf(val - bf2f(hi));
            }
        } else {
            // k in [512,576): conv cols (block-diagonal per head) + zero pad
#pragma unroll
            for (int it = 0; it < 16; ++it) {
                int nl = it * 4 + (tid >> 6);
                int j  = tid & 63;
                float val = 0.f;
                if (j < 40 && (j / 10) == h)
                    val = w_conv[((size_t)h * 10 + (j % 10)) * 512 + a0 + nl];
                size_t o = ((size_t)h * 512 + a0 + nl) * KAUG + 512 + j;
                unsigned short hi = f2bf(val);
                Whi[o] = hi; Wlo[o] = f2bf(val - bf2f(hi));
            }
        }
    }
}

// ---------- fused MFMA GEMM (both paths) + (+dec_a, tanh, *v, reduce-A) -> energy ----------
// Balance x locality swizzle: xcd = id&7 (HW round-robins consecutive ids over XCDs),
// tile = (id>>7)*8 + xcd -> a tile's 16 ntile-blocks are consecutive WITHIN one XCD's
// stream (enc A-slab stays L2-resident, r5-verified), while tiles deal round-robin
// across XCDs with mtile descending (LPT: every XCD gets 4 tiles of each mtile; r6's
// id-order LPT alone blew FETCH to 428 MB, r5's locality alone unbalanced 3x).
__global__ __launch_bounds__(256) void k_gemm(
    const float* __restrict__ enc,
    const unsigned short* __restrict__ Chi, const unsigned short* __restrict__ Clo,
    const unsigned short* __restrict__ Whi, const unsigned short* __restrict__ Wlo,
    const float* __restrict__ dec_a, const float* __restrict__ vvec,
    const int* __restrict__ xl, float* __restrict__ energy) {
    __shared__ unsigned short lsAhi[4096], lsAlo[4096];
    __shared__ unsigned short lsBhi[4096], lsBlo[4096];
    const int id = blockIdx.x;                    // 6144
    const int xcd = id & 7;
    const int s = id >> 3;
    const int ntile = s & 15;
    const int tile = (s >> 4) * 8 + xcd;          // [0,384), XCD-strided
    const int mtile = 11 - (tile >> 5);           // descending: p-tiles first (LPT)
    const int b = tile & 31;
    const int tid = threadIdx.x;
    const int lane = tid & 63, wave = tid >> 6;
    const int wm = wave >> 1, wn = wave & 1;
    const int m0 = mtile * 128, n0 = ntile * 128;
    const int xlen = xl[b];

    f32x4 acc[4][4];
#pragma unroll
    for (int i = 0; i < 4; i++)
#pragma unroll
        for (int j = 0; j < 4; j++) acc[i][j] = (f32x4){0.f, 0.f, 0.f, 0.f};

    const int row = tid >> 2;
    const int ko  = (tid & 3) * 8;
    const size_t bbase = ((size_t)n0 + row) * KAUG + ko;
    const size_t cbase = ((size_t)b * TP + m0 + row) * 64 + ko;
    const int l1 = tid * 8;                       // wave-uniform + lane*16B
    const int l2 = l1 + 2048;
    const int ar = wm * 64, br = wn * 64;
    const int fo = (lane & 15) * 32 + (lane >> 4) * 8;

    const float* ap0 = enc + ((size_t)b * TT + m0 + row) * 512 + ko;
    const float* ap1 = ap0 + (size_t)64 * 512;

    if (m0 + 128 <= xlen) {
        // ================= v-path: 1-product =================
        float4 fa0 = *(const float4*)(ap0);
        float4 fa1 = *(const float4*)(ap0 + 4);
        float4 fa2 = *(const float4*)(ap1);
        float4 fa3 = *(const float4*)(ap1 + 4);
        for (int ks = 0; ks < 18; ++ks) {
            const int k0 = ks * 32;
            __syncthreads();
            glds16(Whi + bbase + k0,                     &lsBhi[l1]);
            glds16(Whi + bbase + k0 + (size_t)64 * KAUG, &lsBhi[l2]);
            if (ks < 16) {
                uint4 w0, w1;
                w0.x = pkbf(fa0.x, fa0.y); w0.y = pkbf(fa0.z, fa0.w);
                w0.z = pkbf(fa1.x, fa1.y); w0.w = pkbf(fa1.z, fa1.w);
                w1.x = pkbf(fa2.x, fa2.y); w1.y = pkbf(fa2.z, fa2.w);
                w1.z = pkbf(fa3.x, fa3.y); w1.w = pkbf(fa3.z, fa3.w);
                *reinterpret_cast<uint4*>(&lsAhi[l1]) = w0;
                *reinterpret_cast<uint4*>(&lsAhi[l2]) = w1;
            } else {
                glds16(Chi + cbase + (ks - 16) * 32,        &lsAhi[l1]);
                glds16(Chi + cbase + (ks - 16) * 32 + 4096, &lsAhi[l2]);
            }
            asm volatile("s_waitcnt vmcnt(0)" ::: "memory");
            __syncthreads();

            bf16x8 ah[4], bh[4];
#pragma unroll
            for (int i = 0; i < 4; i++) {
                ah[i] = *(const bf16x8*)&lsAhi[(ar + i * 16) * 32 + fo];
                bh[i] = *(const bf16x8*)&lsBhi[(br + i * 16) * 32 + fo];
            }
            // prefetch next enc slab: hidden under MFMA, outside barrier drain
            if (ks < 15) {
                const int nk = k0 + 32;
                fa0 = *(const float4*)(ap0 + nk);
                fa1 = *(const float4*)(ap0 + nk + 4);
                fa2 = *(const float4*)(ap1 + nk);
                fa3 = *(const float4*)(ap1 + nk + 4);
            }
#pragma unroll
            for (int i = 0; i < 4; i++)
#pragma unroll
                for (int j = 0; j < 4; j++)
                    acc[i][j] = __builtin_amdgcn_mfma_f32_16x16x32_bf16(ah[i], bh[j], acc[i][j], 0, 0, 0);
        }
    } else {
        // ================= p-path: 3-product split-bf16 =================
        const bool g1 = (m0 + row + 64) < TT;     // rows >= 1500 fed zeros
        const float4 z4 = {0.f, 0.f, 0.f, 0.f};
        bool corr[4];
#pragma unroll
        for (int i = 0; i < 4; i++) corr[i] = (m0 + ar + i * 16 + 16) > xlen;
        float4 fa0 = *(const float4*)(ap0);
        float4 fa1 = *(const float4*)(ap0 + 4);
        float4 fa2 = g1 ? *(const float4*)(ap1) : z4;
        float4 fa3 = g1 ? *(const float4*)(ap1 + 4) : z4;
        for (int ks = 0; ks < 18; ++ks) {
            const int k0 = ks * 32;
            __syncthreads();
            glds16(Whi + bbase + k0,                     &lsBhi[l1]);
            glds16(Whi + bbase + k0 + (size_t)64 * KAUG, &lsBhi[l2]);
            glds16(Wlo + bbase + k0,                     &lsBlo[l1]);
            glds16(Wlo + bbase + k0 + (size_t)64 * KAUG, &lsBlo[l2]);
            if (ks < 16) {
                uint4 h0, h1, e0, e1;
                split2(fa0.x, fa0.y, h0.x, e0.x); split2(fa0.z, fa0.w, h0.y, e0.y);
                split2(fa1.x, fa1.y, h0.z, e0.z); split2(fa1.z, fa1.w, h0.w, e0.w);
                split2(fa2.x, fa2.y, h1.x, e1.x); split2(fa2.z, fa2.w, h1.y, e1.y);
                split2(fa3.x, fa3.y, h1.z, e1.z); split2(fa3.z, fa3.w, h1.w, e1.w);
                *reinterpret_cast<uint4*>(&lsAhi[l1]) = h0;
                *reinterpret_cast<uint4*>(&lsAhi[l2]) = h1;
                *reinterpret_cast<uint4*>(&lsAlo[l1]) = e0;
                *reinterpret_cast<uint4*>(&lsAlo[l2]) = e1;
            } else {
                glds16(Chi + cbase + (ks - 16) * 32,        &lsAhi[l1]);
                glds16(Chi + cbase + (ks - 16) * 32 + 4096, &lsAhi[l2]);
                glds16(Clo + cbase + (ks - 16) * 32,        &lsAlo[l1]);
                glds16(Clo + cbase + (ks - 16) * 32 + 4096, &lsAlo[l2]);
            }
            asm volatile("s_waitcnt vmcnt(0)" ::: "memory");
            __syncthreads();

            bf16x8 ah[4], al[4], bh[4], bl[4];
#pragma unroll
            for (int i = 0; i < 4; i++) {
                ah[i] = *(const bf16x8*)&lsAhi[(ar + i * 16) * 32 + fo];
                al[i] = *(const bf16x8*)&lsAlo[(ar + i * 16) * 32 + fo];
                bh[i] = *(const bf16x8*)&lsBhi[(br + i * 16) * 32 + fo];
                bl[i] = *(const bf16x8*)&lsBlo[(br + i * 16) * 32 + fo];
            }
            if (ks < 15) {
                const int nk = k0 + 32;
                fa0 = *(const float4*)(ap0 + nk);
                fa1 = *(const float4*)(ap0 + nk + 4);
                fa2 = g1 ? *(const float4*)(ap1 + nk) : z4;
                fa3 = g1 ? *(const float4*)(ap1 + nk + 4) : z4;
            }
#pragma unroll
            for (int i = 0; i < 4; i++) {
#pragma unroll
                for (int j = 0; j < 4; j++)
                    acc[i][j] = __builtin_amdgcn_mfma_f32_16x16x32_bf16(ah[i], bh[j], acc[i][j], 0, 0, 0);
                if (corr[i]) {
#pragma unroll
                    for (int j = 0; j < 4; j++) {
                        acc[i][j] = __builtin_amdgcn_mfma_f32_16x16x32_bf16(ah[i], bl[j], acc[i][j], 0, 0, 0);
                        acc[i][j] = __builtin_amdgcn_mfma_f32_16x16x32_bf16(al[i], bh[j], acc[i][j], 0, 0, 0);
                    }
                }
            }
        }
    }

    // Epilogue: x = acc + dec_a[b][n]; energy += tanh(x)*v[n], reduced over head's A-dim
    const int h = ntile >> 2;
    const int kg = lane >> 4;
    float dv[4], vv[4];
#pragma unroll
    for (int j = 0; j < 4; j++) {
        int ng = n0 + wn * 64 + j * 16 + (lane & 15);
        dv[j] = dec_a[(size_t)b * NN + ng];
        vv[j] = vvec[ng];
    }
#pragma unroll
    for (int i = 0; i < 4; i++) {
        float part[4] = {0.f, 0.f, 0.f, 0.f};
#pragma unroll
        for (int j = 0; j < 4; j++)
#pragma unroll
            for (int r = 0; r < 4; r++)
                part[r] += tanh_fast(acc[i][j][r] + dv[j]) * vv[j];
#pragma unroll
        for (int r = 0; r < 4; r++) {
            float s = part[r];
            s += __shfl_xor(s, 1, 64);
            s += __shfl_xor(s, 2, 64);
            s += __shfl_xor(s, 4, 64);
            s += __shfl_xor(s, 8, 64);
            if ((lane & 15) == 0) {
                int t = m0 + wm * 64 + i * 16 + kg * 4 + r;
                if (t < TT)
                    atomicAdd(&energy[((size_t)b * HH + h) * TP + t], s);
            }
        }
    }
}

// ---------- masked softmax over time (replicates energy * (+1 / -1024) mask) ----------
__global__ __launch_bounds__(1024) void k_softmax(const float* __restrict__ energy,
                                                  const int* __restrict__ x_lens,
                                                  float* __restrict__ aw) {
    const int b = blockIdx.x >> 2, h = blockIdx.x & 3;
    const int tid = threadIdx.x;
    __shared__ float sE[TT];
    __shared__ float red[1024];
    const int xlen = x_lens[b];
    float lmax = -3.4e38f;
    for (int t = tid; t < TT; t += 1024) {
        float e = energy[((size_t)b * HH + h) * TP + t];
        float m = (t < xlen) ? e : e * -1024.0f;
        sE[t] = m;
        lmax = fmaxf(lmax, m);
    }
    red[tid] = lmax; __syncthreads();
    for (int s = 512; s > 0; s >>= 1) { if (tid < s) red[tid] = fmaxf(red[tid], red[tid + s]); __syncthreads(); }
    float mx = red[0]; __syncthreads();
    float lsum = 0.f;
    for (int t = tid; t < TT; t += 1024) {
        float ex = __expf(sE[t] - mx);
        sE[t] = ex; lsum += ex;
    }
    red[tid] = lsum; __syncthreads();
    for (int s = 512; s > 0; s >>= 1) { if (tid < s) red[tid] += red[tid + s]; __syncthreads(); }
    float rs = 1.0f / red[0];
    for (int t = tid; t < TT; t += 1024)
        aw[((size_t)b * TT + t) * HH + h] = sE[t] * rs;
}

// ---------- ctx_h[b][h][e] = sum_t aw[b][t][h] * enc[b][t][e] ----------
// 768 blocks (64-t chunks x 32 b), float4 e-cols, 2-way t-split + LDS reduce.
// Chunks whose aw stripe is exactly 0 (fp32 softmax underflow) skip -- exact.
__global__ __launch_bounds__(256) void k_ctx(const float* __restrict__ enc,
                                             const float* __restrict__ aw,
                                             float* __restrict__ ctx_h) {
    const int chunk = blockIdx.x, b = blockIdx.y;   // 24 x 32
    const int t0 = chunk * 64;
    const int nt = (TT - t0 < 64) ? (TT - t0) : 64;
    __shared__ float sA[64 * 4];
    __shared__ float4 red4[128][4];
    __shared__ int s_nz;
    const int tid = threadIdx.x;
    if (tid == 0) s_nz = 0;
    __syncthreads();
    for (int i = tid; i < nt * 4; i += 256) {
        float w = aw[((size_t)b * TT + t0) * HH + i];
        sA[i] = w;
        if (w != 0.f) s_nz = 1;            // race-benign: all writers store 1
    }
    __syncthreads();
    if (!s_nz) return;
    const int e4 = (tid & 127) * 4;
    const int tg = tid >> 7;               // 0..1
    const float* ep = enc + ((size_t)b * TT + t0) * EE + e4;
    float acc[4][4] = {};                  // [h][e-comp]
#pragma unroll 4
    for (int tt = tg; tt < nt; tt += 2) {
        float4 ev = *reinterpret_cast<const float4*>(ep + (size_t)tt * EE);
        float w0 = sA[tt * 4 + 0], w1 = sA[tt * 4 + 1];
        float w2 = sA[tt * 4 + 2], w3 = sA[tt * 4 + 3];
        acc[0][0] += w0 * ev.x; acc[0][1] += w0 * ev.y; acc[0][2] += w0 * ev.z; acc[0][3] += w0 * ev.w;
        acc[1][0] += w1 * ev.x; acc[1][1] += w1 * ev.y; acc[1][2] += w1 * ev.z; acc[1][3] += w1 * ev.w;
        acc[2][0] += w2 * ev.x; acc[2][1] += w2 * ev.y; acc[2][2] += w2 * ev.z; acc[2][3] += w2 * ev.w;
        acc[3][0] += w3 * ev.x; acc[3][1] += w3 * ev.y; acc[3][2] += w3 * ev.z; acc[3][3] += w3 * ev.w;
    }
    if (tg == 1) {
#pragma unroll
        for (int h = 0; h < 4; ++h)
            red4[tid & 127][h] = make_float4(acc[h][0], acc[h][1], acc[h][2], acc[h][3]);
    }
    __syncthreads();
    if (tg == 0) {
#pragma unroll
        for (int h = 0; h < 4; ++h) {
            float4 o = red4[tid][h];
            float* dst = &ctx_h[((size_t)b * HH + h) * EE + e4];
            atomicAdd(dst + 0, acc[h][0] + o.x);
            atomicAdd(dst + 1, acc[h][1] + o.y);
            atomicAdd(dst + 2, acc[h][2] + o.z);
            atomicAdd(dst + 3, acc[h][3] + o.w);
        }
    }
}

// ---------- ctx = ctx_h @ w_mha + b_mha ----------
__global__ __launch_bounds__(256) void k_mha(const float* __restrict__ ctx_h,
                                             const float* __restrict__ w_mha,
                                             const float* __restrict__ b_mha,
                                             float* __restrict__ out) {
    __shared__ float sred[256];
    const int tid = threadIdx.x;
    const int b  = blockIdx.x >> 2;
    const int eo = ((blockIdx.x & 3) << 7) + (tid & 127);
    const int kg = tid >> 7;                   // 0..1, 1024 k each
    const float* c = ctx_h + (size_t)b * NN + kg * 1024;
    const float* w = w_mha + ((size_t)kg * 1024) * EE + eo;
    float acc = 0.f;
#pragma unroll 8
    for (int k = 0; k < 1024; ++k) acc += c[k] * w[(size_t)k * EE];
    sred[tid] = acc;
    __syncthreads();
    if (tid < 128)
        out[(size_t)b * EE + eo] = b_mha[eo] + sred[tid] + sred[tid + 128];
}

extern "C" void kernel_launch(void* const* d_in, const int* in_sizes, int n_in,
                              void* d_out, int out_size, void* d_ws, size_t ws_size,
                              hipStream_t stream) {
    (void)in_sizes; (void)n_in; (void)out_size;
    const float* enc    = (const float*)d_in[0];
    const int*   xlen   = (const int*)d_in[1];
    const float* dec    = (const float*)d_in[2];
    const float* aw_in  = (const float*)d_in[3];
    const float* w_enc  = (const float*)d_in[4];
    const float* b_enc  = (const float*)d_in[5];
    const float* w_dec  = (const float*)d_in[6];
    const float* w_conv = (const float*)d_in[7];
    const float* convk  = (const float*)d_in[8];
    const float* v      = (const float*)d_in[9];
    const float* w_mha  = (const float*)d_in[10];
    const float* b_mha  = (const float*)d_in[11];
    float* out = (float*)d_out;

    // ws layout (~18.6 MB)
    char* ws = (char*)d_ws;
    unsigned short* Whi = (unsigned short*)ws;                   // 2,359,296 B
    unsigned short* Wlo = (unsigned short*)(ws + 2359296);       // 2,359,296 B
    unsigned short* Chi = (unsigned short*)(ws + 4718592);       // 6,291,456 B
    unsigned short* Clo = (unsigned short*)(ws + 11010048);      // 6,291,456 B
    float* dec_a  = (float*)(ws + 17301504);                     //   262,144 B
    float* energy = (float*)(ws + 17563648);                     //   786,432 B
    float* ctx_h  = (float*)(ws + 18350080);                     //   262,144 B (contiguous after energy)
    (void)ws_size;

    k_prep<<<dim3(PREP_TOTAL), 256, 0, stream>>>(dec, aw_in, w_enc, b_enc,
                                                 w_dec, w_conv, convk,
                                                 Whi, Wlo, Chi, Clo, dec_a, energy);
    k_gemm<<<dim3(6144), 256, 0, stream>>>(enc, Chi, Clo, Whi, Wlo, dec_a, v, xlen, energy);
    k_softmax<<<dim3(BB * HH), 1024, 0, stream>>>(energy, xlen, out + 16384);
    k_ctx <<<dim3(24, BB), 256, 0, stream>>>(enc, out + 16384, ctx_h);
    k_mha <<<dim3(128), 256, 0, stream>>>(ctx_h, w_mha, b_mha, out);
}